// Round 10
// baseline (75.937 us; speedup 1.0000x reference)
//
#include <hip/hip_runtime.h>
#include <math.h>

#define NPIX  6400
#define NH    8
#define KSPLIT 5
#define KPS   1280        // keys per split
#define KPW   320         // keys per wave
#define DITER 5           // double-tile iterations (64 keys each)
#define LOG2E 1.4426950408889634f
#define DEFER_THR 11.5f   // log2-units (~8 nats)

typedef _Float16 f16x8 __attribute__((ext_vector_type(8)));
typedef __fp16   h16x2 __attribute__((ext_vector_type(2)));   // native cvt_pkrtz type
typedef __attribute__((ext_vector_type(16))) float f16v;
typedef __attribute__((ext_vector_type(4)))  float f4v;
typedef __attribute__((ext_vector_type(4)))  int   i4v;
typedef unsigned int u32x2 __attribute__((ext_vector_type(2)));

__device__ __forceinline__ f16v zero16() {
    f16v z = {0,0,0,0,0,0,0,0,0,0,0,0,0,0,0,0};
    return z;
}
__device__ __forceinline__ float exp2fast(float x) {
    float r;
    asm("v_exp_f32 %0, %1" : "=v"(r) : "v"(x));
    return r;
}
__device__ __forceinline__ unsigned pkrtz(float a, float b) {
    h16x2 h = __builtin_amdgcn_cvt_pkrtz(a, b);
    return __builtin_bit_cast(unsigned, h);
}
__device__ __forceinline__ float xhalf_max(float x) {
    unsigned a = __float_as_uint(x), b = a;
    u32x2 r = __builtin_amdgcn_permlane32_swap(a, b, false, false);
    return fmaxf(__uint_as_float(r[0]), __uint_as_float(r[1]));
}
__device__ __forceinline__ float xhalf_sum(float x) {
    unsigned a = __float_as_uint(x), b = a;
    u32x2 r = __builtin_amdgcn_permlane32_swap(a, b, false, false);
    return __uint_as_float(r[0]) + __uint_as_float(r[1]);
}
#define PL32SWAP(a, b) { u32x2 _r = __builtin_amdgcn_permlane32_swap((a), (b), false, false); (a) = _r[0]; (b) = _r[1]; }

// ---------------------------------------------------------------------------
// prep_qk: Qs (head-summed, *log2e) and K -> fp16, stored [pixel][64f].
// grid = 32 f-pairs x 25 pixel-chunks = 800 blocks.
// ---------------------------------------------------------------------------
__global__ __launch_bounds__(256)
void prep_qk(const float* __restrict__ X, const float* __restrict__ prevQ,
             const float* __restrict__ WQ_task, const float* __restrict__ BQ_task,
             const float* __restrict__ WQ_tm1, const float* __restrict__ WQ_x,
             const float* __restrict__ BQ,
             const float* __restrict__ WK_task, const float* __restrict__ BK_task,
             const float* __restrict__ WK_x, const float* __restrict__ BK,
             _Float16* __restrict__ QG, _Float16* __restrict__ KG) {
    int f0 = (blockIdx.x / 25) * 2;                 // 0,2,..,62
    int p  = (blockIdx.x % 25) * 256 + threadIdx.x;
    float qv[2], kv[2];
#pragma unroll
    for (int j = 0; j < 2; ++j) {
        int f = f0 + j;
        float x = X[f * NPIX + p];
        kv[j] = WK_task[f] * (WK_x[f] * x + BK[f]) + BK_task[f];
        float wqx_x = WQ_x[f] * x;
        float a = 0.f;
#pragma unroll
        for (int h = 0; h < NH; ++h) {
            int hf = h * 64 + f;
            float inner = WQ_tm1[hf] * prevQ[hf * NPIX + p] + wqx_x + BQ[hf];
            a += WQ_task[hf] * inner + BQ_task[hf];
        }
        qv[j] = a * LOG2E;                          // fold log2(e) for exp2 softmax
    }
    QG[p * 64 + f0] = (_Float16)qv[0]; QG[p * 64 + f0 + 1] = (_Float16)qv[1];
    KG[p * 64 + f0] = (_Float16)kv[0]; KG[p * 64 + f0 + 1] = (_Float16)kv[1];
}

// ---------------------------------------------------------------------------
// xpad: zero-padded fp16 transpose of X: Xp2[82][82][64f].  Border rows/cols
// are zero so the conv needs no boundary branches.  grid = 27 blocks.
// ---------------------------------------------------------------------------
__global__ __launch_bounds__(256)
void xpad(const float* __restrict__ X, _Float16* __restrict__ Xp2) {
    int idx = blockIdx.x * 256 + threadIdx.x;       // < 6724 = 82*82
    if (idx >= 82 * 82) return;
    int xx = idx / 82, yy = idx % 82;
    _Float16* dst = Xp2 + idx * 64;
    if (xx == 0 || xx == 81 || yy == 0 || yy == 81) {
        f16x8 z = {0, 0, 0, 0, 0, 0, 0, 0};
#pragma unroll
        for (int j = 0; j < 8; ++j) *(f16x8*)(dst + j * 8) = z;
    } else {
        int p = (xx - 1) * 80 + (yy - 1);
#pragma unroll
        for (int j = 0; j < 8; ++j) {
            f16x8 v;
#pragma unroll
            for (int i = 0; i < 8; ++i) v[i] = (_Float16)X[(j * 8 + i) * NPIX + p];
            *(f16x8*)(dst + j * 8) = v;
        }
    }
}

// ---------------------------------------------------------------------------
// wprep: Wt[pos9][ft4][c32][fi16] = WV_task[c] * Vconv_w[c][ft*16+fi][pos] fp16,
// plus biasV[c] = WV_task[c]*bc[c] + BV_task[c].  1 block.
// ---------------------------------------------------------------------------
__global__ __launch_bounds__(256)
void wprep(const float* __restrict__ Wc, const float* __restrict__ bc,
           const float* __restrict__ WV_task, const float* __restrict__ BV_task,
           _Float16* __restrict__ Wt, float* __restrict__ biasV) {
    for (int e = threadIdx.x; e < 9 * 4 * 32 * 16; e += 256) {
        int pos = e / 2048;
        int rem = e - pos * 2048;
        int ft = rem / 512;
        int rem2 = rem - ft * 512;
        int c = rem2 / 16, fi = rem2 - (rem2 / 16) * 16;
        int f = ft * 16 + fi;
        Wt[e] = (_Float16)(WV_task[c] * Wc[c * 576 + f * 9 + pos]);
    }
    if (threadIdx.x < 32)
        biasV[threadIdx.x] = WV_task[threadIdx.x] * bc[threadIdx.x] + BV_task[threadIdx.x];
}

// ---------------------------------------------------------------------------
// conv_mfma: V = conv3x3 via MFMA.  One wave = one 32-pixel tile (row x,
// y0 in {0,32,48}; y 48-63 written twice with identical values - benign).
// D[c][p] = sum_{pos,f} Wt[c][f,pos] * Xp2[x+dx][y0+lq+dy][f]: 36 MFMA/tile.
// grid = 60 blocks x 4 waves = 240 tiles.
// ---------------------------------------------------------------------------
__global__ __launch_bounds__(256)
void conv_mfma(const _Float16* __restrict__ Xp2, const _Float16* __restrict__ Wt,
               const float* __restrict__ biasV, _Float16* __restrict__ VG) {
    const int tid = threadIdx.x;
    const int w = tid >> 6, l = tid & 63;
    const int lq = l & 31, h = l >> 5;
    int tile = blockIdx.x * 4 + w;                  // < 240
    int x = tile / 3, y0i = tile % 3;
    int y0 = (y0i == 0) ? 0 : ((y0i == 1) ? 32 : 48);

    f16v o = zero16();
#pragma unroll
    for (int pos = 0; pos < 9; ++pos) {
        int dx = pos / 3, dy = pos % 3;
        const _Float16* xb = Xp2 + ((x + dx) * 82 + (y0 + lq + dy)) * 64 + h * 8;
        const _Float16* wb = Wt + (pos * 4 * 32 + lq) * 16 + h * 8;
#pragma unroll
        for (int ft = 0; ft < 4; ++ft) {
            f16x8 a = *(const f16x8*)(wb + ft * 512);
            f16x8 b = *(const f16x8*)(xb + ft * 16);
            o = __builtin_amdgcn_mfma_f32_32x32x16_f16(a, b, o, 0, 0, 0);
        }
    }
    int p = x * 80 + y0 + lq;
#pragma unroll
    for (int r = 0; r < 16; ++r) {
        int c = (r & 3) + 8 * (r >> 2) + 4 * h;
        VG[c * NPIX + p] = (_Float16)(o[r] + biasV[c]);
    }
}

// ---------------------------------------------------------------------------
// attn_mfma: verbatim round-8 kernel (known-good ~35us).  LDS-free flash
// attention, fp16 32x32x16 MFMA, K register dbuf, exp2 softmax, defer-max.
// grid = 200 q-tiles x 5 key-splits = 1000 blocks x 4 waves.
// ---------------------------------------------------------------------------
__global__ __launch_bounds__(256, 3)
void attn_mfma(const _Float16* __restrict__ QG,
               const _Float16* __restrict__ KG,
               const _Float16* __restrict__ VG,
               float* __restrict__ PmG, float* __restrict__ PlG,
               _Float16* __restrict__ PaccG) {
    __shared__ __align__(16) char lds[17408];   // macc 16384 | mm 512 | ll 512

    const int tid = threadIdx.x;
    const int w = tid >> 6, l = tid & 63;
    const int lq = l & 31, h = l >> 5;
    const int qt = blockIdx.x / KSPLIT, ks = blockIdx.x % KSPLIT;
    const int qbase = qt * 32;
    const int wkbase = ks * KPS + w * KPW;

    f16x8 qf[4];
    {
        const _Float16* qp = QG + (qbase + lq) * 64 + h * 8;
#pragma unroll
        for (int c = 0; c < 4; ++c) qf[c] = *(const f16x8*)(qp + c * 16);
    }

    const _Float16* kg = KG + (wkbase + lq) * 64 + h * 8;
    const _Float16* vg = VG + lq * NPIX + wkbase + h * 8;

    f16v o = zero16();
    float m = -INFINITY, lsum = 0.f;

    f16x8 kA[2][4], kB[2][4];
#pragma unroll
    for (int i = 0; i < 4; ++i) {
        kA[0][i] = *(const f16x8*)(kg + 16 * i);
        kB[0][i] = *(const f16x8*)(kg + 2048 + 16 * i);
    }

#pragma unroll
    for (int it = 0; it < DITER; ++it) {
        const int cur = it & 1, nxt = cur ^ 1;

        f16x8 vA0 = *(const f16x8*)(vg +  0);
        f16x8 vA1 = *(const f16x8*)(vg + 16);
        f16x8 vB0 = *(const f16x8*)(vg + 32);
        f16x8 vB1 = *(const f16x8*)(vg + 48);
        vg += 64;

        if (it + 1 < DITER) {
            kg += 4096;
#pragma unroll
            for (int i = 0; i < 4; ++i) {
                kA[nxt][i] = *(const f16x8*)(kg + 16 * i);
                kB[nxt][i] = *(const f16x8*)(kg + 2048 + 16 * i);
            }
        }

        f16v sA = zero16(), sB = zero16();
#pragma unroll
        for (int i = 0; i < 4; ++i) {
            sA = __builtin_amdgcn_mfma_f32_32x32x16_f16(kA[cur][i], qf[i], sA, 0, 0, 0);
            sB = __builtin_amdgcn_mfma_f32_32x32x16_f16(kB[cur][i], qf[i], sB, 0, 0, 0);
        }

        float t8[8];
#pragma unroll
        for (int r = 0; r < 8; ++r)
            t8[r] = fmaxf(fmaxf(sA[2 * r], sA[2 * r + 1]),
                          fmaxf(sB[2 * r], sB[2 * r + 1]));
        float mx = fmaxf(fmaxf(fmaxf(t8[0], t8[1]), fmaxf(t8[2], t8[3])),
                         fmaxf(fmaxf(t8[4], t8[5]), fmaxf(t8[6], t8[7])));
        mx = xhalf_max(mx);
        if (__any(mx > m + DEFER_THR)) {
            float mn = fmaxf(m, mx);
            float sc = exp2fast(m - mn);
            lsum *= sc;
#pragma unroll
            for (int r = 0; r < 16; ++r) o[r] *= sc;
            m = mn;
        }
#pragma unroll
        for (int r = 0; r < 16; ++r) sA[r] = exp2fast(sA[r] - m);
#pragma unroll
        for (int r = 0; r < 16; ++r) sB[r] = exp2fast(sB[r] - m);
        float ps = 0.f;
#pragma unroll
        for (int r = 0; r < 16; ++r) ps += sA[r] + sB[r];
        lsum += xhalf_sum(ps);

        {
            unsigned p0 = pkrtz(sA[0],  sA[1]),  p1 = pkrtz(sA[2],  sA[3]);
            unsigned p2 = pkrtz(sA[4],  sA[5]),  p3 = pkrtz(sA[6],  sA[7]);
            unsigned p4 = pkrtz(sA[8],  sA[9]),  p5 = pkrtz(sA[10], sA[11]);
            unsigned p6 = pkrtz(sA[12], sA[13]), p7 = pkrtz(sA[14], sA[15]);
            PL32SWAP(p0, p2); PL32SWAP(p1, p3); PL32SWAP(p4, p6); PL32SWAP(p5, p7);
            i4v f0 = { (int)p0, (int)p1, (int)p2, (int)p3 };
            i4v f1 = { (int)p4, (int)p5, (int)p6, (int)p7 };
            o = __builtin_amdgcn_mfma_f32_32x32x16_f16(vA0, __builtin_bit_cast(f16x8, f0), o, 0, 0, 0);
            o = __builtin_amdgcn_mfma_f32_32x32x16_f16(vA1, __builtin_bit_cast(f16x8, f1), o, 0, 0, 0);
        }
        {
            unsigned p0 = pkrtz(sB[0],  sB[1]),  p1 = pkrtz(sB[2],  sB[3]);
            unsigned p2 = pkrtz(sB[4],  sB[5]),  p3 = pkrtz(sB[6],  sB[7]);
            unsigned p4 = pkrtz(sB[8],  sB[9]),  p5 = pkrtz(sB[10], sB[11]);
            unsigned p6 = pkrtz(sB[12], sB[13]), p7 = pkrtz(sB[14], sB[15]);
            PL32SWAP(p0, p2); PL32SWAP(p1, p3); PL32SWAP(p4, p6); PL32SWAP(p5, p7);
            i4v f0 = { (int)p0, (int)p1, (int)p2, (int)p3 };
            i4v f1 = { (int)p4, (int)p5, (int)p6, (int)p7 };
            o = __builtin_amdgcn_mfma_f32_32x32x16_f16(vB0, __builtin_bit_cast(f16x8, f0), o, 0, 0, 0);
            o = __builtin_amdgcn_mfma_f32_32x32x16_f16(vB1, __builtin_bit_cast(f16x8, f1), o, 0, 0, 0);
        }
    }

    float* mm = (float*)(lds + 16384);
    float* ll = (float*)(lds + 16896);
#pragma unroll
    for (int rg = 0; rg < 4; ++rg) {
        f4v val = { o[rg * 4 + 0], o[rg * 4 + 1], o[rg * 4 + 2], o[rg * 4 + 3] };
        int cb = rg * 8 + 4 * h;
        int byte = (w * 32 + lq) * 128 + ((cb * 4) ^ ((lq & 7) << 4));
        *(f4v*)(lds + byte) = val;
    }
    if (l < 32) { mm[w * 32 + lq] = m; ll[w * 32 + lq] = lsum; }
    __syncthreads();

    {
        int q = tid >> 3, cb = (tid & 7) * 4;
        float m0 = mm[q], m1 = mm[32 + q], m2 = mm[64 + q], m3 = mm[96 + q];
        float M = fmaxf(fmaxf(m0, m1), fmaxf(m2, m3));
        float e0 = exp2fast(m0 - M), e1 = exp2fast(m1 - M);
        float e2 = exp2fast(m2 - M), e3 = exp2fast(m3 - M);
        float L = ll[q] * e0 + ll[32 + q] * e1 + ll[64 + q] * e2 + ll[96 + q] * e3;
        float rL = 1.f / L;
        int swz = (q & 7) << 4;
        f4v a0 = *(f4v*)(lds + (0 * 32 + q) * 128 + ((cb * 4) ^ swz));
        f4v a1 = *(f4v*)(lds + (1 * 32 + q) * 128 + ((cb * 4) ^ swz));
        f4v a2 = *(f4v*)(lds + (2 * 32 + q) * 128 + ((cb * 4) ^ swz));
        f4v a3 = *(f4v*)(lds + (3 * 32 + q) * 128 + ((cb * 4) ^ swz));
        int qg = qbase + q;
        _Float16 outp[4];
        outp[0] = (_Float16)((a0[0] * e0 + a1[0] * e1 + a2[0] * e2 + a3[0] * e3) * rL);
        outp[1] = (_Float16)((a0[1] * e0 + a1[1] * e1 + a2[1] * e2 + a3[1] * e3) * rL);
        outp[2] = (_Float16)((a0[2] * e0 + a1[2] * e1 + a2[2] * e2 + a3[2] * e3) * rL);
        outp[3] = (_Float16)((a0[3] * e0 + a1[3] * e1 + a2[3] * e2 + a3[3] * e3) * rL);
        *(unsigned long long*)(PaccG + ks * 204800 + qg * 32 + cb) =
            *(unsigned long long*)outp;
        if ((tid & 7) == 0) { PmG[ks * NPIX + qg] = M; PlG[ks * NPIX + qg] = L; }
    }
}

// ---------------------------------------------------------------------------
// merge_out (c-major): consecutive lanes walk q for a fixed c -> coalesced
// out writes and Pm/Pl reads.  grid = 32 c x 25 q-chunks = 800 blocks.
// ---------------------------------------------------------------------------
__global__ __launch_bounds__(256)
void merge_out(const float* __restrict__ Pm, const float* __restrict__ Pl,
               const _Float16* __restrict__ Pacc, float* __restrict__ out) {
    int c = blockIdx.x / 25;
    int q = (blockIdx.x % 25) * 256 + threadIdx.x;
    float mv[KSPLIT];
    float M = -INFINITY;
#pragma unroll
    for (int ksi = 0; ksi < KSPLIT; ++ksi) { mv[ksi] = Pm[ksi * NPIX + q]; M = fmaxf(M, mv[ksi]); }
    float den = 0.f, num = 0.f;
#pragma unroll
    for (int ksi = 0; ksi < KSPLIT; ++ksi) {
        float wgt = Pl[ksi * NPIX + q] * exp2fast(mv[ksi] - M);
        den += wgt;
        num += (float)Pacc[ksi * 204800 + q * 32 + c] * wgt;
    }
    out[c * NPIX + q] = num / den;
}

// ---------------------------------------------------------------------------
extern "C" void kernel_launch(void* const* d_in, const int* in_sizes, int n_in,
                              void* d_out, int out_size, void* d_ws, size_t ws_size,
                              hipStream_t stream) {
    const float* X       = (const float*)d_in[0];
    const float* WQ_task = (const float*)d_in[1];
    const float* BQ_task = (const float*)d_in[2];
    const float* WK_task = (const float*)d_in[3];
    const float* BK_task = (const float*)d_in[4];
    const float* WV_task = (const float*)d_in[5];
    const float* BV_task = (const float*)d_in[6];
    const float* WQ_tm1  = (const float*)d_in[7];
    const float* WQ_x    = (const float*)d_in[8];
    const float* BQ      = (const float*)d_in[9];
    const float* WK_x    = (const float*)d_in[10];
    const float* BK      = (const float*)d_in[11];
    const float* prev_Q  = (const float*)d_in[12];
    const float* Vconv_w = (const float*)d_in[13];
    const float* Vconv_b = (const float*)d_in[14];

    char* wsb = (char*)d_ws;
    _Float16* QG    = (_Float16*)(wsb + 0);        //  819200
    _Float16* KG    = (_Float16*)(wsb + 819200);   //  819200
    _Float16* VG    = (_Float16*)(wsb + 1638400);  //  409600
    _Float16* Xp2   = (_Float16*)(wsb + 2048000);  //  860672 (82*82*64*2)
    _Float16* Wt    = (_Float16*)(wsb + 2909184);  //   36864
    float*    biasV = (float*)(wsb + 2946048);     //     128
    float*    PmG   = (float*)(wsb + 2946176);     //  128000
    float*    PlG   = (float*)(wsb + 3074176);     //  128000
    _Float16* PaccG = (_Float16*)(wsb + 3202176);  // 2048000 -> 5250176 total

    prep_qk<<<800, 256, 0, stream>>>(X, prev_Q, WQ_task, BQ_task, WQ_tm1, WQ_x, BQ,
                                     WK_task, BK_task, WK_x, BK, QG, KG);
    xpad<<<27, 256, 0, stream>>>(X, Xp2);
    wprep<<<1, 256, 0, stream>>>(Vconv_w, Vconv_b, WV_task, BV_task, Wt, biasV);
    conv_mfma<<<60, 256, 0, stream>>>(Xp2, Wt, biasV, VG);
    attn_mfma<<<200 * KSPLIT, 256, 0, stream>>>(QG, KG, VG, PmG, PlG, PaccG);
    merge_out<<<800, 256, 0, stream>>>(PmG, PlG, PaccG, (float*)d_out);
}

// Round 11
// 61.054 us; speedup vs baseline: 1.2438x; 1.2438x over previous
//
#include <hip/hip_runtime.h>
#include <math.h>

#define NPIX  6400
#define NH    8
#define KSPLIT 5
#define KPS   1280        // keys per split
#define KPW   320         // keys per wave
#define DITER 5           // double-tile iterations (64 keys each)
#define LOG2E 1.4426950408889634f
#define DEFER_THR 11.5f   // log2-units (~8 nats)

typedef _Float16 f16x8 __attribute__((ext_vector_type(8)));
typedef __fp16   h16x2 __attribute__((ext_vector_type(2)));   // native cvt_pkrtz type
typedef __attribute__((ext_vector_type(16))) float f16v;
typedef __attribute__((ext_vector_type(4)))  float f4v;
typedef __attribute__((ext_vector_type(4)))  int   i4v;
typedef unsigned int u32x2 __attribute__((ext_vector_type(2)));

__device__ __forceinline__ f16v zero16() {
    f16v z = {0,0,0,0,0,0,0,0,0,0,0,0,0,0,0,0};
    return z;
}
__device__ __forceinline__ float exp2fast(float x) {
    float r;
    asm("v_exp_f32 %0, %1" : "=v"(r) : "v"(x));
    return r;
}
__device__ __forceinline__ unsigned pkrtz(float a, float b) {
    h16x2 h = __builtin_amdgcn_cvt_pkrtz(a, b);
    return __builtin_bit_cast(unsigned, h);
}
__device__ __forceinline__ float xhalf_max(float x) {
    unsigned a = __float_as_uint(x), b = a;
    u32x2 r = __builtin_amdgcn_permlane32_swap(a, b, false, false);
    return fmaxf(__uint_as_float(r[0]), __uint_as_float(r[1]));
}
__device__ __forceinline__ float xhalf_sum(float x) {
    unsigned a = __float_as_uint(x), b = a;
    u32x2 r = __builtin_amdgcn_permlane32_swap(a, b, false, false);
    return __uint_as_float(r[0]) + __uint_as_float(r[1]);
}
#define PL32SWAP(a, b) { u32x2 _r = __builtin_amdgcn_permlane32_swap((a), (b), false, false); (a) = _r[0]; (b) = _r[1]; }

// ---------------------------------------------------------------------------
// prep_all: one launch, three independent block ranges (no cross-deps):
//  blocks 0..799 : Qs (head-summed, *log2e) and K -> fp16 [pixel][64f]
//  blocks 800..826: Xp2[82][82][64] zero-padded fp16 transpose of X
//  block  827    : Wt[pos][ft][c][fi] fp16 conv weights (WV folded) + biasV
// ---------------------------------------------------------------------------
__global__ __launch_bounds__(256)
void prep_all(const float* __restrict__ X, const float* __restrict__ prevQ,
              const float* __restrict__ WQ_task, const float* __restrict__ BQ_task,
              const float* __restrict__ WQ_tm1, const float* __restrict__ WQ_x,
              const float* __restrict__ BQ,
              const float* __restrict__ WK_task, const float* __restrict__ BK_task,
              const float* __restrict__ WK_x, const float* __restrict__ BK,
              const float* __restrict__ Wc, const float* __restrict__ bc,
              const float* __restrict__ WV_task, const float* __restrict__ BV_task,
              _Float16* __restrict__ QG, _Float16* __restrict__ KG,
              _Float16* __restrict__ Xp2, _Float16* __restrict__ Wt,
              float* __restrict__ biasV) {
    int bid = blockIdx.x;
    if (bid < 800) {
        int f0 = (bid / 25) * 2;                    // 0,2,..,62
        int p  = (bid % 25) * 256 + threadIdx.x;
        float qv[2], kv[2];
#pragma unroll
        for (int j = 0; j < 2; ++j) {
            int f = f0 + j;
            float x = X[f * NPIX + p];
            kv[j] = WK_task[f] * (WK_x[f] * x + BK[f]) + BK_task[f];
            float wqx_x = WQ_x[f] * x;
            float a = 0.f;
#pragma unroll
            for (int h = 0; h < NH; ++h) {
                int hf = h * 64 + f;
                float inner = WQ_tm1[hf] * prevQ[hf * NPIX + p] + wqx_x + BQ[hf];
                a += WQ_task[hf] * inner + BQ_task[hf];
            }
            qv[j] = a * LOG2E;                      // fold log2(e) for exp2 softmax
        }
        QG[p * 64 + f0] = (_Float16)qv[0]; QG[p * 64 + f0 + 1] = (_Float16)qv[1];
        KG[p * 64 + f0] = (_Float16)kv[0]; KG[p * 64 + f0 + 1] = (_Float16)kv[1];
    } else if (bid < 827) {
        int idx = (bid - 800) * 256 + threadIdx.x;  // < 6724 = 82*82
        if (idx >= 82 * 82) return;
        int xx = idx / 82, yy = idx % 82;
        _Float16* dst = Xp2 + idx * 64;
        if (xx == 0 || xx == 81 || yy == 0 || yy == 81) {
            f16x8 z = {0, 0, 0, 0, 0, 0, 0, 0};
#pragma unroll
            for (int j = 0; j < 8; ++j) *(f16x8*)(dst + j * 8) = z;
        } else {
            int p = (xx - 1) * 80 + (yy - 1);
#pragma unroll
            for (int j = 0; j < 8; ++j) {
                f16x8 v;
#pragma unroll
                for (int i = 0; i < 8; ++i) v[i] = (_Float16)X[(j * 8 + i) * NPIX + p];
                *(f16x8*)(dst + j * 8) = v;
            }
        }
    } else {
        for (int e = threadIdx.x; e < 9 * 4 * 32 * 16; e += 256) {
            int pos = e / 2048;
            int rem = e - pos * 2048;
            int ft = rem / 512;
            int rem2 = rem - ft * 512;
            int c = rem2 / 16, fi = rem2 - (rem2 / 16) * 16;
            int f = ft * 16 + fi;
            Wt[e] = (_Float16)(WV_task[c] * Wc[c * 576 + f * 9 + pos]);
        }
        if (threadIdx.x < 32)
            biasV[threadIdx.x] = WV_task[threadIdx.x] * bc[threadIdx.x] + BV_task[threadIdx.x];
    }
}

// ---------------------------------------------------------------------------
// conv_mfma: V = conv3x3 via MFMA.  ONE WAVE per block, 240 blocks -> spreads
// over 240 CUs (was 60).  y0 in {0,32,48}: rows 48-63 written twice, benign.
// ---------------------------------------------------------------------------
__global__ __launch_bounds__(64)
void conv_mfma(const _Float16* __restrict__ Xp2, const _Float16* __restrict__ Wt,
               const float* __restrict__ biasV, _Float16* __restrict__ VG) {
    const int l = threadIdx.x;
    const int lq = l & 31, h = l >> 5;
    int tile = blockIdx.x;                          // < 240
    int x = tile / 3, y0i = tile % 3;
    int y0 = (y0i == 0) ? 0 : ((y0i == 1) ? 32 : 48);

    f16v o = zero16();
#pragma unroll
    for (int pos = 0; pos < 9; ++pos) {
        int dx = pos / 3, dy = pos % 3;
        const _Float16* xb = Xp2 + ((x + dx) * 82 + (y0 + lq + dy)) * 64 + h * 8;
        const _Float16* wb = Wt + (pos * 4 * 32 + lq) * 16 + h * 8;
#pragma unroll
        for (int ft = 0; ft < 4; ++ft) {
            f16x8 a = *(const f16x8*)(wb + ft * 512);
            f16x8 b = *(const f16x8*)(xb + ft * 16);
            o = __builtin_amdgcn_mfma_f32_32x32x16_f16(a, b, o, 0, 0, 0);
        }
    }
    int p = x * 80 + y0 + lq;
#pragma unroll
    for (int r = 0; r < 16; ++r) {
        int c = (r & 3) + 8 * (r >> 2) + 4 * h;
        VG[c * NPIX + p] = (_Float16)(o[r] + biasV[c]);
    }
}

// ---------------------------------------------------------------------------
// attn_mfma: verbatim round-8 kernel (known ~35us).  LDS-free flash attention,
// fp16 32x32x16 MFMA, K register dbuf, exp2 softmax, defer-max.
// grid = 200 q-tiles x 5 key-splits = 1000 blocks x 4 waves.
// ---------------------------------------------------------------------------
__global__ __launch_bounds__(256, 3)
void attn_mfma(const _Float16* __restrict__ QG,
               const _Float16* __restrict__ KG,
               const _Float16* __restrict__ VG,
               float* __restrict__ PmG, float* __restrict__ PlG,
               _Float16* __restrict__ PaccG) {
    __shared__ __align__(16) char lds[17408];   // macc 16384 | mm 512 | ll 512

    const int tid = threadIdx.x;
    const int w = tid >> 6, l = tid & 63;
    const int lq = l & 31, h = l >> 5;
    const int qt = blockIdx.x / KSPLIT, ks = blockIdx.x % KSPLIT;
    const int qbase = qt * 32;
    const int wkbase = ks * KPS + w * KPW;

    f16x8 qf[4];
    {
        const _Float16* qp = QG + (qbase + lq) * 64 + h * 8;
#pragma unroll
        for (int c = 0; c < 4; ++c) qf[c] = *(const f16x8*)(qp + c * 16);
    }

    const _Float16* kg = KG + (wkbase + lq) * 64 + h * 8;
    const _Float16* vg = VG + lq * NPIX + wkbase + h * 8;

    f16v o = zero16();
    float m = -INFINITY, lsum = 0.f;

    f16x8 kA[2][4], kB[2][4];
#pragma unroll
    for (int i = 0; i < 4; ++i) {
        kA[0][i] = *(const f16x8*)(kg + 16 * i);
        kB[0][i] = *(const f16x8*)(kg + 2048 + 16 * i);
    }

#pragma unroll
    for (int it = 0; it < DITER; ++it) {
        const int cur = it & 1, nxt = cur ^ 1;

        f16x8 vA0 = *(const f16x8*)(vg +  0);
        f16x8 vA1 = *(const f16x8*)(vg + 16);
        f16x8 vB0 = *(const f16x8*)(vg + 32);
        f16x8 vB1 = *(const f16x8*)(vg + 48);
        vg += 64;

        if (it + 1 < DITER) {
            kg += 4096;
#pragma unroll
            for (int i = 0; i < 4; ++i) {
                kA[nxt][i] = *(const f16x8*)(kg + 16 * i);
                kB[nxt][i] = *(const f16x8*)(kg + 2048 + 16 * i);
            }
        }

        f16v sA = zero16(), sB = zero16();
#pragma unroll
        for (int i = 0; i < 4; ++i) {
            sA = __builtin_amdgcn_mfma_f32_32x32x16_f16(kA[cur][i], qf[i], sA, 0, 0, 0);
            sB = __builtin_amdgcn_mfma_f32_32x32x16_f16(kB[cur][i], qf[i], sB, 0, 0, 0);
        }

        float t8[8];
#pragma unroll
        for (int r = 0; r < 8; ++r)
            t8[r] = fmaxf(fmaxf(sA[2 * r], sA[2 * r + 1]),
                          fmaxf(sB[2 * r], sB[2 * r + 1]));
        float mx = fmaxf(fmaxf(fmaxf(t8[0], t8[1]), fmaxf(t8[2], t8[3])),
                         fmaxf(fmaxf(t8[4], t8[5]), fmaxf(t8[6], t8[7])));
        mx = xhalf_max(mx);
        if (__any(mx > m + DEFER_THR)) {
            float mn = fmaxf(m, mx);
            float sc = exp2fast(m - mn);
            lsum *= sc;
#pragma unroll
            for (int r = 0; r < 16; ++r) o[r] *= sc;
            m = mn;
        }
#pragma unroll
        for (int r = 0; r < 16; ++r) sA[r] = exp2fast(sA[r] - m);
#pragma unroll
        for (int r = 0; r < 16; ++r) sB[r] = exp2fast(sB[r] - m);
        float ps = 0.f;
#pragma unroll
        for (int r = 0; r < 16; ++r) ps += sA[r] + sB[r];
        lsum += xhalf_sum(ps);

        {
            unsigned p0 = pkrtz(sA[0],  sA[1]),  p1 = pkrtz(sA[2],  sA[3]);
            unsigned p2 = pkrtz(sA[4],  sA[5]),  p3 = pkrtz(sA[6],  sA[7]);
            unsigned p4 = pkrtz(sA[8],  sA[9]),  p5 = pkrtz(sA[10], sA[11]);
            unsigned p6 = pkrtz(sA[12], sA[13]), p7 = pkrtz(sA[14], sA[15]);
            PL32SWAP(p0, p2); PL32SWAP(p1, p3); PL32SWAP(p4, p6); PL32SWAP(p5, p7);
            i4v f0 = { (int)p0, (int)p1, (int)p2, (int)p3 };
            i4v f1 = { (int)p4, (int)p5, (int)p6, (int)p7 };
            o = __builtin_amdgcn_mfma_f32_32x32x16_f16(vA0, __builtin_bit_cast(f16x8, f0), o, 0, 0, 0);
            o = __builtin_amdgcn_mfma_f32_32x32x16_f16(vA1, __builtin_bit_cast(f16x8, f1), o, 0, 0, 0);
        }
        {
            unsigned p0 = pkrtz(sB[0],  sB[1]),  p1 = pkrtz(sB[2],  sB[3]);
            unsigned p2 = pkrtz(sB[4],  sB[5]),  p3 = pkrtz(sB[6],  sB[7]);
            unsigned p4 = pkrtz(sB[8],  sB[9]),  p5 = pkrtz(sB[10], sB[11]);
            unsigned p6 = pkrtz(sB[12], sB[13]), p7 = pkrtz(sB[14], sB[15]);
            PL32SWAP(p0, p2); PL32SWAP(p1, p3); PL32SWAP(p4, p6); PL32SWAP(p5, p7);
            i4v f0 = { (int)p0, (int)p1, (int)p2, (int)p3 };
            i4v f1 = { (int)p4, (int)p5, (int)p6, (int)p7 };
            o = __builtin_amdgcn_mfma_f32_32x32x16_f16(vB0, __builtin_bit_cast(f16x8, f0), o, 0, 0, 0);
            o = __builtin_amdgcn_mfma_f32_32x32x16_f16(vB1, __builtin_bit_cast(f16x8, f1), o, 0, 0, 0);
        }
    }

    float* mm = (float*)(lds + 16384);
    float* ll = (float*)(lds + 16896);
#pragma unroll
    for (int rg = 0; rg < 4; ++rg) {
        f4v val = { o[rg * 4 + 0], o[rg * 4 + 1], o[rg * 4 + 2], o[rg * 4 + 3] };
        int cb = rg * 8 + 4 * h;
        int byte = (w * 32 + lq) * 128 + ((cb * 4) ^ ((lq & 7) << 4));
        *(f4v*)(lds + byte) = val;
    }
    if (l < 32) { mm[w * 32 + lq] = m; ll[w * 32 + lq] = lsum; }
    __syncthreads();

    {
        int q = tid >> 3, cb = (tid & 7) * 4;
        float m0 = mm[q], m1 = mm[32 + q], m2 = mm[64 + q], m3 = mm[96 + q];
        float M = fmaxf(fmaxf(m0, m1), fmaxf(m2, m3));
        float e0 = exp2fast(m0 - M), e1 = exp2fast(m1 - M);
        float e2 = exp2fast(m2 - M), e3 = exp2fast(m3 - M);
        float L = ll[q] * e0 + ll[32 + q] * e1 + ll[64 + q] * e2 + ll[96 + q] * e3;
        float rL = 1.f / L;
        int swz = (q & 7) << 4;
        f4v a0 = *(f4v*)(lds + (0 * 32 + q) * 128 + ((cb * 4) ^ swz));
        f4v a1 = *(f4v*)(lds + (1 * 32 + q) * 128 + ((cb * 4) ^ swz));
        f4v a2 = *(f4v*)(lds + (2 * 32 + q) * 128 + ((cb * 4) ^ swz));
        f4v a3 = *(f4v*)(lds + (3 * 32 + q) * 128 + ((cb * 4) ^ swz));
        int qg = qbase + q;
        _Float16 outp[4];
        outp[0] = (_Float16)((a0[0] * e0 + a1[0] * e1 + a2[0] * e2 + a3[0] * e3) * rL);
        outp[1] = (_Float16)((a0[1] * e0 + a1[1] * e1 + a2[1] * e2 + a3[1] * e3) * rL);
        outp[2] = (_Float16)((a0[2] * e0 + a1[2] * e1 + a2[2] * e2 + a3[2] * e3) * rL);
        outp[3] = (_Float16)((a0[3] * e0 + a1[3] * e1 + a2[3] * e2 + a3[3] * e3) * rL);
        *(unsigned long long*)(PaccG + ks * 204800 + qg * 32 + cb) =
            *(unsigned long long*)outp;
        if ((tid & 7) == 0) { PmG[ks * NPIX + qg] = M; PlG[ks * NPIX + qg] = L; }
    }
}

// ---------------------------------------------------------------------------
// merge_out: R8-verbatim indexing — consecutive lanes = consecutive c so Pacc
// reads are fully coalesced (out writes uncoalesced but only ~13MB of lines).
// ---------------------------------------------------------------------------
__global__ __launch_bounds__(256)
void merge_out(const float* __restrict__ Pm, const float* __restrict__ Pl,
               const _Float16* __restrict__ Pacc, float* __restrict__ out) {
    int idx = blockIdx.x * 256 + threadIdx.x;       // < 204800
    int q = idx >> 5, c = idx & 31;
    float mv[KSPLIT];
    float M = -INFINITY;
#pragma unroll
    for (int ksi = 0; ksi < KSPLIT; ++ksi) { mv[ksi] = Pm[ksi * NPIX + q]; M = fmaxf(M, mv[ksi]); }
    float den = 0.f, num = 0.f;
#pragma unroll
    for (int ksi = 0; ksi < KSPLIT; ++ksi) {
        float wgt = Pl[ksi * NPIX + q] * exp2fast(mv[ksi] - M);
        den += wgt;
        num += (float)Pacc[ksi * 204800 + q * 32 + c] * wgt;
    }
    out[c * NPIX + q] = num / den;
}

// ---------------------------------------------------------------------------
extern "C" void kernel_launch(void* const* d_in, const int* in_sizes, int n_in,
                              void* d_out, int out_size, void* d_ws, size_t ws_size,
                              hipStream_t stream) {
    const float* X       = (const float*)d_in[0];
    const float* WQ_task = (const float*)d_in[1];
    const float* BQ_task = (const float*)d_in[2];
    const float* WK_task = (const float*)d_in[3];
    const float* BK_task = (const float*)d_in[4];
    const float* WV_task = (const float*)d_in[5];
    const float* BV_task = (const float*)d_in[6];
    const float* WQ_tm1  = (const float*)d_in[7];
    const float* WQ_x    = (const float*)d_in[8];
    const float* BQ      = (const float*)d_in[9];
    const float* WK_x    = (const float*)d_in[10];
    const float* BK      = (const float*)d_in[11];
    const float* prev_Q  = (const float*)d_in[12];
    const float* Vconv_w = (const float*)d_in[13];
    const float* Vconv_b = (const float*)d_in[14];

    char* wsb = (char*)d_ws;
    _Float16* QG    = (_Float16*)(wsb + 0);        //  819200
    _Float16* KG    = (_Float16*)(wsb + 819200);   //  819200
    _Float16* VG    = (_Float16*)(wsb + 1638400);  //  409600
    _Float16* Xp2   = (_Float16*)(wsb + 2048000);  //  860672 (82*82*64*2)
    _Float16* Wt    = (_Float16*)(wsb + 2909184);  //   36864
    float*    biasV = (float*)(wsb + 2946048);     //     128
    float*    PmG   = (float*)(wsb + 2946176);     //  128000
    float*    PlG   = (float*)(wsb + 3074176);     //  128000
    _Float16* PaccG = (_Float16*)(wsb + 3202176);  // 2048000 -> 5250176 total

    prep_all<<<828, 256, 0, stream>>>(X, prev_Q, WQ_task, BQ_task, WQ_tm1, WQ_x, BQ,
                                      WK_task, BK_task, WK_x, BK,
                                      Vconv_w, Vconv_b, WV_task, BV_task,
                                      QG, KG, Xp2, Wt, biasV);
    conv_mfma<<<240, 64, 0, stream>>>(Xp2, Wt, biasV, VG);
    attn_mfma<<<200 * KSPLIT, 256, 0, stream>>>(QG, KG, VG, PmG, PlG, PaccG);
    merge_out<<<800, 256, 0, stream>>>(PmG, PlG, PaccG, (float*)d_out);
}

// Round 12
// 41.226 us; speedup vs baseline: 1.8420x; 1.4810x over previous
//
#include <hip/hip_runtime.h>
#include <math.h>

#define NPIX  6400
#define NH    8
#define KSPLIT 5
#define KPS   1280        // keys per split
#define KPW   320         // keys per wave
#define DITER 5           // double-tile iterations (64 keys each)
#define LOG2E 1.4426950408889634f
#define DEFER_THR 11.5f   // log2-units (~8 nats)

typedef _Float16 f16x8 __attribute__((ext_vector_type(8)));
typedef __fp16   h16x2 __attribute__((ext_vector_type(2)));   // native cvt_pkrtz type
typedef __attribute__((ext_vector_type(16))) float f16v;
typedef __attribute__((ext_vector_type(4)))  float f4v;
typedef __attribute__((ext_vector_type(4)))  int   i4v;
typedef unsigned int u32x2 __attribute__((ext_vector_type(2)));

__device__ __forceinline__ f16v zero16() {
    f16v z = {0,0,0,0,0,0,0,0,0,0,0,0,0,0,0,0};
    return z;
}
__device__ __forceinline__ float exp2fast(float x) {
    float r;
    asm("v_exp_f32 %0, %1" : "=v"(r) : "v"(x));
    return r;
}
__device__ __forceinline__ unsigned pkrtz(float a, float b) {
    h16x2 h = __builtin_amdgcn_cvt_pkrtz(a, b);
    return __builtin_bit_cast(unsigned, h);
}
__device__ __forceinline__ float xhalf_max(float x) {
    unsigned a = __float_as_uint(x), b = a;
    u32x2 r = __builtin_amdgcn_permlane32_swap(a, b, false, false);
    return fmaxf(__uint_as_float(r[0]), __uint_as_float(r[1]));
}
__device__ __forceinline__ float xhalf_sum(float x) {
    unsigned a = __float_as_uint(x), b = a;
    u32x2 r = __builtin_amdgcn_permlane32_swap(a, b, false, false);
    return __uint_as_float(r[0]) + __uint_as_float(r[1]);
}
#define PL32SWAP(a, b) { u32x2 _r = __builtin_amdgcn_permlane32_swap((a), (b), false, false); (a) = _r[0]; (b) = _r[1]; }

// ---------------------------------------------------------------------------
// prep_all: one launch, three independent block ranges:
//  blocks 0..199 : Qs (head-summed, *log2e) and K -> fp16, FRAGMENT-MAJOR:
//                  QT/KT[(g*NPIX + p)*8 + j] for feature f = 8g+j.
//                  One thread = one pixel x one 8-feature group (16B stores).
//  blocks 200..226: Xp2[82][82][64] zero-padded fp16 transpose of X
//  block  227    : Wt fp16 conv weights (WV folded) + biasV
// ---------------------------------------------------------------------------
__global__ __launch_bounds__(256)
void prep_all(const float* __restrict__ X, const float* __restrict__ prevQ,
              const float* __restrict__ WQ_task, const float* __restrict__ BQ_task,
              const float* __restrict__ WQ_tm1, const float* __restrict__ WQ_x,
              const float* __restrict__ BQ,
              const float* __restrict__ WK_task, const float* __restrict__ BK_task,
              const float* __restrict__ WK_x, const float* __restrict__ BK,
              const float* __restrict__ Wc, const float* __restrict__ bc,
              const float* __restrict__ WV_task, const float* __restrict__ BV_task,
              _Float16* __restrict__ QT, _Float16* __restrict__ KT,
              _Float16* __restrict__ Xp2, _Float16* __restrict__ Wt,
              float* __restrict__ biasV) {
    int bid = blockIdx.x;
    if (bid < 200) {
        int g = bid / 25;                           // feature group 0..7
        int p = (bid % 25) * 256 + threadIdx.x;
        f16x8 qv8, kv8;
#pragma unroll
        for (int j = 0; j < 8; ++j) {
            int f = g * 8 + j;
            float x = X[f * NPIX + p];
            float kv = WK_task[f] * (WK_x[f] * x + BK[f]) + BK_task[f];
            float wqx_x = WQ_x[f] * x;
            float a = 0.f;
#pragma unroll
            for (int h = 0; h < NH; ++h) {
                int hf = h * 64 + f;
                float inner = WQ_tm1[hf] * prevQ[hf * NPIX + p] + wqx_x + BQ[hf];
                a += WQ_task[hf] * inner + BQ_task[hf];
            }
            qv8[j] = (_Float16)(a * LOG2E);         // fold log2(e) for exp2 softmax
            kv8[j] = (_Float16)kv;
        }
        *(f16x8*)(QT + (g * NPIX + p) * 8) = qv8;
        *(f16x8*)(KT + (g * NPIX + p) * 8) = kv8;
    } else if (bid < 227) {
        int idx = (bid - 200) * 256 + threadIdx.x;  // < 6724 = 82*82
        if (idx >= 82 * 82) return;
        int xx = idx / 82, yy = idx % 82;
        _Float16* dst = Xp2 + idx * 64;
        if (xx == 0 || xx == 81 || yy == 0 || yy == 81) {
            f16x8 z = {0, 0, 0, 0, 0, 0, 0, 0};
#pragma unroll
            for (int j = 0; j < 8; ++j) *(f16x8*)(dst + j * 8) = z;
        } else {
            int p = (xx - 1) * 80 + (yy - 1);
#pragma unroll
            for (int j = 0; j < 8; ++j) {
                f16x8 v;
#pragma unroll
                for (int i = 0; i < 8; ++i) v[i] = (_Float16)X[(j * 8 + i) * NPIX + p];
                *(f16x8*)(dst + j * 8) = v;
            }
        }
    } else {
        for (int e = threadIdx.x; e < 9 * 4 * 32 * 16; e += 256) {
            int pos = e / 2048;
            int rem = e - pos * 2048;
            int ft = rem / 512;
            int rem2 = rem - ft * 512;
            int c = rem2 / 16, fi = rem2 - (rem2 / 16) * 16;
            int f = ft * 16 + fi;
            Wt[e] = (_Float16)(WV_task[c] * Wc[c * 576 + f * 9 + pos]);
        }
        if (threadIdx.x < 32)
            biasV[threadIdx.x] = WV_task[threadIdx.x] * bc[threadIdx.x] + BV_task[threadIdx.x];
    }
}

// ---------------------------------------------------------------------------
// conv_mfma: V = conv3x3 via MFMA, one wave/block (240 blocks).  Output into
// fragment-major VT[((key>>4)*2 + ((key>>3)&1))*256 + c*8 + (key&7)].
// ---------------------------------------------------------------------------
__global__ __launch_bounds__(64)
void conv_mfma(const _Float16* __restrict__ Xp2, const _Float16* __restrict__ Wt,
               const float* __restrict__ biasV, _Float16* __restrict__ VT) {
    const int l = threadIdx.x;
    const int lq = l & 31, h = l >> 5;
    int tile = blockIdx.x;                          // < 240
    int x = tile / 3, y0i = tile % 3;
    int y0 = (y0i == 0) ? 0 : ((y0i == 1) ? 32 : 48);

    f16v o = zero16();
#pragma unroll
    for (int pos = 0; pos < 9; ++pos) {
        int dx = pos / 3, dy = pos % 3;
        const _Float16* xb = Xp2 + ((x + dx) * 82 + (y0 + lq + dy)) * 64 + h * 8;
        const _Float16* wb = Wt + (pos * 4 * 32 + lq) * 16 + h * 8;
#pragma unroll
        for (int ft = 0; ft < 4; ++ft) {
            f16x8 a = *(const f16x8*)(wb + ft * 512);
            f16x8 b = *(const f16x8*)(xb + ft * 16);
            o = __builtin_amdgcn_mfma_f32_32x32x16_f16(a, b, o, 0, 0, 0);
        }
    }
    int p = x * 80 + y0 + lq;
    int vbase = ((p >> 4) * 2 + ((p >> 3) & 1)) * 256 + (p & 7);
#pragma unroll
    for (int r = 0; r < 16; ++r) {
        int c = (r & 3) + 8 * (r >> 2) + 4 * h;
        VT[vbase + c * 8] = (_Float16)(o[r] + biasV[c]);
    }
}

// ---------------------------------------------------------------------------
// attn_mfma: R8 structure; ONLY the Q/K/V load addressing changed to the
// fragment-major layouts (every VMEM load now coalesced: consecutive lanes ->
// consecutive 16B, 8 lines/instr instead of 32).
// grid = 200 q-tiles x 5 key-splits = 1000 blocks x 4 waves.
// ---------------------------------------------------------------------------
__global__ __launch_bounds__(256, 3)
void attn_mfma(const _Float16* __restrict__ QT,
               const _Float16* __restrict__ KT,
               const _Float16* __restrict__ VT,
               float* __restrict__ PmG, float* __restrict__ PlG,
               _Float16* __restrict__ PaccG) {
    __shared__ __align__(16) char lds[17408];   // macc 16384 | mm 512 | ll 512

    const int tid = threadIdx.x;
    const int w = tid >> 6, l = tid & 63;
    const int lq = l & 31, h = l >> 5;
    const int qt = blockIdx.x / KSPLIT, ks = blockIdx.x % KSPLIT;
    const int qbase = qt * 32;
    const int wkbase = ks * KPS + w * KPW;

    // Q fragments: coalesced (two 512B runs per load)
    f16x8 qf[4];
    {
        const _Float16* qp = QT + (h * NPIX + qbase + lq) * 8;
#pragma unroll
        for (int c = 0; c < 4; ++c) qf[c] = *(const f16x8*)(qp + c * (2 * NPIX * 8));
    }

    const _Float16* kg = KT + (h * NPIX + wkbase + lq) * 8;
    const _Float16* vg = VT + wkbase * 32 + (h * 32 + lq) * 8;

    f16v o = zero16();
    float m = -INFINITY, lsum = 0.f;

    f16x8 kA[2][4], kB[2][4];
#pragma unroll
    for (int i = 0; i < 4; ++i) {
        kA[0][i] = *(const f16x8*)(kg + i * (2 * NPIX * 8));
        kB[0][i] = *(const f16x8*)(kg + i * (2 * NPIX * 8) + 256);
    }

#pragma unroll
    for (int it = 0; it < DITER; ++it) {
        const int cur = it & 1, nxt = cur ^ 1;

        // V loads: fully contiguous 1KB per instruction
        f16x8 vA0 = *(const f16x8*)(vg +    0);
        f16x8 vA1 = *(const f16x8*)(vg +  512);
        f16x8 vB0 = *(const f16x8*)(vg + 1024);
        f16x8 vB1 = *(const f16x8*)(vg + 1536);
        vg += 2048;

        if (it + 1 < DITER) {
            kg += 512;
#pragma unroll
            for (int i = 0; i < 4; ++i) {
                kA[nxt][i] = *(const f16x8*)(kg + i * (2 * NPIX * 8));
                kB[nxt][i] = *(const f16x8*)(kg + i * (2 * NPIX * 8) + 256);
            }
        }

        f16v sA = zero16(), sB = zero16();
#pragma unroll
        for (int i = 0; i < 4; ++i) {
            sA = __builtin_amdgcn_mfma_f32_32x32x16_f16(kA[cur][i], qf[i], sA, 0, 0, 0);
            sB = __builtin_amdgcn_mfma_f32_32x32x16_f16(kB[cur][i], qf[i], sB, 0, 0, 0);
        }

        float t8[8];
#pragma unroll
        for (int r = 0; r < 8; ++r)
            t8[r] = fmaxf(fmaxf(sA[2 * r], sA[2 * r + 1]),
                          fmaxf(sB[2 * r], sB[2 * r + 1]));
        float mx = fmaxf(fmaxf(fmaxf(t8[0], t8[1]), fmaxf(t8[2], t8[3])),
                         fmaxf(fmaxf(t8[4], t8[5]), fmaxf(t8[6], t8[7])));
        mx = xhalf_max(mx);
        if (__any(mx > m + DEFER_THR)) {
            float mn = fmaxf(m, mx);
            float sc = exp2fast(m - mn);
            lsum *= sc;
#pragma unroll
            for (int r = 0; r < 16; ++r) o[r] *= sc;
            m = mn;
        }
#pragma unroll
        for (int r = 0; r < 16; ++r) sA[r] = exp2fast(sA[r] - m);
#pragma unroll
        for (int r = 0; r < 16; ++r) sB[r] = exp2fast(sB[r] - m);
        float ps = 0.f;
#pragma unroll
        for (int r = 0; r < 16; ++r) ps += sA[r] + sB[r];
        lsum += xhalf_sum(ps);

        {
            unsigned p0 = pkrtz(sA[0],  sA[1]),  p1 = pkrtz(sA[2],  sA[3]);
            unsigned p2 = pkrtz(sA[4],  sA[5]),  p3 = pkrtz(sA[6],  sA[7]);
            unsigned p4 = pkrtz(sA[8],  sA[9]),  p5 = pkrtz(sA[10], sA[11]);
            unsigned p6 = pkrtz(sA[12], sA[13]), p7 = pkrtz(sA[14], sA[15]);
            PL32SWAP(p0, p2); PL32SWAP(p1, p3); PL32SWAP(p4, p6); PL32SWAP(p5, p7);
            i4v f0 = { (int)p0, (int)p1, (int)p2, (int)p3 };
            i4v f1 = { (int)p4, (int)p5, (int)p6, (int)p7 };
            o = __builtin_amdgcn_mfma_f32_32x32x16_f16(vA0, __builtin_bit_cast(f16x8, f0), o, 0, 0, 0);
            o = __builtin_amdgcn_mfma_f32_32x32x16_f16(vA1, __builtin_bit_cast(f16x8, f1), o, 0, 0, 0);
        }
        {
            unsigned p0 = pkrtz(sB[0],  sB[1]),  p1 = pkrtz(sB[2],  sB[3]);
            unsigned p2 = pkrtz(sB[4],  sB[5]),  p3 = pkrtz(sB[6],  sB[7]);
            unsigned p4 = pkrtz(sB[8],  sB[9]),  p5 = pkrtz(sB[10], sB[11]);
            unsigned p6 = pkrtz(sB[12], sB[13]), p7 = pkrtz(sB[14], sB[15]);
            PL32SWAP(p0, p2); PL32SWAP(p1, p3); PL32SWAP(p4, p6); PL32SWAP(p5, p7);
            i4v f0 = { (int)p0, (int)p1, (int)p2, (int)p3 };
            i4v f1 = { (int)p4, (int)p5, (int)p6, (int)p7 };
            o = __builtin_amdgcn_mfma_f32_32x32x16_f16(vB0, __builtin_bit_cast(f16x8, f0), o, 0, 0, 0);
            o = __builtin_amdgcn_mfma_f32_32x32x16_f16(vB1, __builtin_bit_cast(f16x8, f1), o, 0, 0, 0);
        }
    }

    float* mm = (float*)(lds + 16384);
    float* ll = (float*)(lds + 16896);
#pragma unroll
    for (int rg = 0; rg < 4; ++rg) {
        f4v val = { o[rg * 4 + 0], o[rg * 4 + 1], o[rg * 4 + 2], o[rg * 4 + 3] };
        int cb = rg * 8 + 4 * h;
        int byte = (w * 32 + lq) * 128 + ((cb * 4) ^ ((lq & 7) << 4));
        *(f4v*)(lds + byte) = val;
    }
    if (l < 32) { mm[w * 32 + lq] = m; ll[w * 32 + lq] = lsum; }
    __syncthreads();

    {
        int q = tid >> 3, cb = (tid & 7) * 4;
        float m0 = mm[q], m1 = mm[32 + q], m2 = mm[64 + q], m3 = mm[96 + q];
        float M = fmaxf(fmaxf(m0, m1), fmaxf(m2, m3));
        float e0 = exp2fast(m0 - M), e1 = exp2fast(m1 - M);
        float e2 = exp2fast(m2 - M), e3 = exp2fast(m3 - M);
        float L = ll[q] * e0 + ll[32 + q] * e1 + ll[64 + q] * e2 + ll[96 + q] * e3;
        float rL = 1.f / L;
        int swz = (q & 7) << 4;
        f4v a0 = *(f4v*)(lds + (0 * 32 + q) * 128 + ((cb * 4) ^ swz));
        f4v a1 = *(f4v*)(lds + (1 * 32 + q) * 128 + ((cb * 4) ^ swz));
        f4v a2 = *(f4v*)(lds + (2 * 32 + q) * 128 + ((cb * 4) ^ swz));
        f4v a3 = *(f4v*)(lds + (3 * 32 + q) * 128 + ((cb * 4) ^ swz));
        int qg = qbase + q;
        _Float16 outp[4];
        outp[0] = (_Float16)((a0[0] * e0 + a1[0] * e1 + a2[0] * e2 + a3[0] * e3) * rL);
        outp[1] = (_Float16)((a0[1] * e0 + a1[1] * e1 + a2[1] * e2 + a3[1] * e3) * rL);
        outp[2] = (_Float16)((a0[2] * e0 + a1[2] * e1 + a2[2] * e2 + a3[2] * e3) * rL);
        outp[3] = (_Float16)((a0[3] * e0 + a1[3] * e1 + a2[3] * e2 + a3[3] * e3) * rL);
        *(unsigned long long*)(PaccG + ks * 204800 + qg * 32 + cb) =
            *(unsigned long long*)outp;
        if ((tid & 7) == 0) { PmG[ks * NPIX + qg] = M; PlG[ks * NPIX + qg] = L; }
    }
}

// ---------------------------------------------------------------------------
// merge_out: consecutive lanes = consecutive c -> coalesced Pacc reads.
// ---------------------------------------------------------------------------
__global__ __launch_bounds__(256)
void merge_out(const float* __restrict__ Pm, const float* __restrict__ Pl,
               const _Float16* __restrict__ Pacc, float* __restrict__ out) {
    int idx = blockIdx.x * 256 + threadIdx.x;       // < 204800
    int q = idx >> 5, c = idx & 31;
    float mv[KSPLIT];
    float M = -INFINITY;
#pragma unroll
    for (int ksi = 0; ksi < KSPLIT; ++ksi) { mv[ksi] = Pm[ksi * NPIX + q]; M = fmaxf(M, mv[ksi]); }
    float den = 0.f, num = 0.f;
#pragma unroll
    for (int ksi = 0; ksi < KSPLIT; ++ksi) {
        float wgt = Pl[ksi * NPIX + q] * exp2fast(mv[ksi] - M);
        den += wgt;
        num += (float)Pacc[ksi * 204800 + q * 32 + c] * wgt;
    }
    out[c * NPIX + q] = num / den;
}

// ---------------------------------------------------------------------------
extern "C" void kernel_launch(void* const* d_in, const int* in_sizes, int n_in,
                              void* d_out, int out_size, void* d_ws, size_t ws_size,
                              hipStream_t stream) {
    const float* X       = (const float*)d_in[0];
    const float* WQ_task = (const float*)d_in[1];
    const float* BQ_task = (const float*)d_in[2];
    const float* WK_task = (const float*)d_in[3];
    const float* BK_task = (const float*)d_in[4];
    const float* WV_task = (const float*)d_in[5];
    const float* BV_task = (const float*)d_in[6];
    const float* WQ_tm1  = (const float*)d_in[7];
    const float* WQ_x    = (const float*)d_in[8];
    const float* BQ      = (const float*)d_in[9];
    const float* WK_x    = (const float*)d_in[10];
    const float* BK      = (const float*)d_in[11];
    const float* prev_Q  = (const float*)d_in[12];
    const float* Vconv_w = (const float*)d_in[13];
    const float* Vconv_b = (const float*)d_in[14];

    char* wsb = (char*)d_ws;
    _Float16* QT    = (_Float16*)(wsb + 0);        //  819200
    _Float16* KT    = (_Float16*)(wsb + 819200);   //  819200
    _Float16* VT    = (_Float16*)(wsb + 1638400);  //  409600
    _Float16* Xp2   = (_Float16*)(wsb + 2048000);  //  860672 (82*82*64*2)
    _Float16* Wt    = (_Float16*)(wsb + 2909184);  //   36864
    float*    biasV = (float*)(wsb + 2946048);     //     128
    float*    PmG   = (float*)(wsb + 2946176);     //  128000
    float*    PlG   = (float*)(wsb + 3074176);     //  128000
    _Float16* PaccG = (_Float16*)(wsb + 3202176);  // 2048000 -> 5250176 total

    prep_all<<<228, 256, 0, stream>>>(X, prev_Q, WQ_task, BQ_task, WQ_tm1, WQ_x, BQ,
                                      WK_task, BK_task, WK_x, BK,
                                      Vconv_w, Vconv_b, WV_task, BV_task,
                                      QT, KT, Xp2, Wt, biasV);
    conv_mfma<<<240, 64, 0, stream>>>(Xp2, Wt, biasV, VT);
    attn_mfma<<<200 * KSPLIT, 256, 0, stream>>>(QT, KT, VT, PmG, PlG, PaccG);
    merge_out<<<800, 256, 0, stream>>>(PmG, PlG, PaccG, (float*)d_out);
}